// Round 2
// 482.612 us; speedup vs baseline: 1.1204x; 1.1204x over previous
//
#include <hip/hip_runtime.h>

// Confirmed device layout (prior session evidence):
//   x:       float32 [BATCH, IN_DIM]   (4096 x 16384)
//   weights: float32 [OUT_DIM, 16]
//   a_idx:   int32   [OUT_DIM]
//   b_idx:   int32   [OUT_DIM]
//   out:     float32 [BATCH, OUT_DIM]
// out[r,c] = k0 + k1*a + k2*b + k3*a*b, a = x[r,a_idx[c]], b = x[r,b_idx[c]],
// k[c] = softmax(weights[c,:]) @ GATE_COEFFS (16x4).

typedef float f32x4 __attribute__((ext_vector_type(4)));

__device__ __constant__ float GC[16][4] = {
    {0.f, 0.f, 0.f, 0.f},  {0.f, 0.f, 0.f, 1.f},
    {0.f, 1.f, 0.f, -1.f}, {0.f, 1.f, 0.f, 0.f},
    {0.f, 0.f, 1.f, -1.f}, {0.f, 0.f, 1.f, 0.f},
    {0.f, 1.f, 1.f, -2.f}, {0.f, 1.f, 1.f, -1.f},
    {1.f, -1.f, -1.f, 1.f},{1.f, -1.f, -1.f, 2.f},
    {1.f, 0.f, -1.f, 0.f}, {1.f, 0.f, -1.f, 1.f},
    {1.f, -1.f, 0.f, 0.f}, {1.f, -1.f, 0.f, 1.f},
    {1.f, 0.f, 0.f, -1.f}, {1.f, 0.f, 0.f, 0.f}};

// async global->LDS, 16B per lane. LDS dest = wave-uniform base + lane*16;
// global source is per-lane. (m97/m104 contract; literal size arg.)
#define ASYNC_COPY_16B(gsrc, ldst)                                        \
  __builtin_amdgcn_global_load_lds(                                       \
      (const __attribute__((address_space(1))) unsigned int*)(gsrc),      \
      (__attribute__((address_space(3))) unsigned int*)(ldst), 16, 0, 0)

__device__ __forceinline__ void softmax_k(const float* __restrict__ wrow,
                                          float& k0, float& k1, float& k2,
                                          float& k3) {
  const float4* wr = (const float4*)wrow;
  float4 q0 = wr[0], q1 = wr[1], q2 = wr[2], q3 = wr[3];
  float w[16] = {q0.x, q0.y, q0.z, q0.w, q1.x, q1.y, q1.z, q1.w,
                 q2.x, q2.y, q2.z, q2.w, q3.x, q3.y, q3.z, q3.w};
  float m = w[0];
#pragma unroll
  for (int i = 1; i < 16; ++i) m = fmaxf(m, w[i]);
  float S = 0.f, s0 = 0.f, s1 = 0.f, s2 = 0.f, s3 = 0.f;
#pragma unroll
  for (int i = 0; i < 16; ++i) {
    float e = expf(w[i] - m);
    S += e;
    s0 = fmaf(e, GC[i][0], s0);
    s1 = fmaf(e, GC[i][1], s1);
    s2 = fmaf(e, GC[i][2], s2);
    s3 = fmaf(e, GC[i][3], s3);
  }
  float inv = 1.f / S;
  k0 = s0 * inv;
  k1 = s1 * inv;
  k2 = s2 * inv;
  k3 = s3 * inv;
}

// ---- meta SoA (fast path): k0[],k1[],k2[],k3[] floats; ai[],bi[] ints ----
__global__ void meta_soa_kernel(const float* __restrict__ weights,
                                const int* __restrict__ a_idx,
                                const int* __restrict__ b_idx,
                                float* __restrict__ k0, float* __restrict__ k1,
                                float* __restrict__ k2, float* __restrict__ k3,
                                int* __restrict__ ai, int* __restrict__ bi,
                                int out_dim) {
  int c = blockIdx.x * blockDim.x + threadIdx.x;
  if (c >= out_dim) return;
  float a, b, d, e;
  softmax_k(weights + (size_t)c * 16, a, b, d, e);
  k0[c] = a;
  k1[c] = b;
  k2[c] = d;
  k3[c] = e;
  ai[c] = a_idx[c];
  bi[c] = b_idx[c];
}

// ---- fast path: persistent 8-row blocks, double-buffered LDS row pipeline.
// 1024 threads (16 waves), 128 KiB LDS -> 1 block/CU, grid = batch/8.
__global__ __launch_bounds__(1024, 4) void logic_fast_kernel(
    const float* __restrict__ x, const float* __restrict__ k0v,
    const float* __restrict__ k1v, const float* __restrict__ k2v,
    const float* __restrict__ k3v, const int* __restrict__ aiv,
    const int* __restrict__ biv, float* __restrict__ out) {
  constexpr int IN = 16384;
  constexpr int OUT = 16384;
  constexpr int R = 8;
  __shared__ float buf[2][IN];  // 128 KiB: two fp32 x-rows

  const int tid = threadIdx.x;
  const int lane = tid & 63;
  const int wv = tid >> 6;
  const size_t row0 = (size_t)blockIdx.x * R;

  // Gather indices are row-invariant: hoist this thread's 16 columns worth
  // (32 VGPRs) so L2 latency never sits on the ds_read critical path.
  int4 Am[4], Bm[4];
#pragma unroll
  for (int i = 0; i < 4; ++i) {
    Am[i] = ((const int4*)aiv)[tid + i * 1024];
    Bm[i] = ((const int4*)biv)[tid + i * 1024];
  }

  // Prologue: stage row 0 into buf[0]. 64 chunks of 1 KiB; 4 per wave.
  {
    const float* src = x + row0 * IN;
#pragma unroll
    for (int s = 0; s < 4; ++s) {
      const int chunk = wv + s * 16;
      ASYNC_COPY_16B(src + chunk * 256 + lane * 4, &buf[0][chunk * 256]);
    }
  }
  __syncthreads();  // vmcnt(0) drain + barrier: row 0 resident

  for (int r = 0; r < R; ++r) {
    // Issue async staging of row r+1 FIRST; HBM latency hides under gather.
    // Write-target buf[(r+1)&1] was last read in iter r-1, sealed by that
    // iter's barrier -> no WAR race.
    if (r + 1 < R) {
      const float* src = x + (row0 + r + 1) * IN;
#pragma unroll
      for (int s = 0; s < 4; ++s) {
        const int chunk = wv + s * 16;
        ASYNC_COPY_16B(src + chunk * 256 + lane * 4,
                       &buf[(r + 1) & 1][chunk * 256]);
      }
    }

    const float* rb = buf[r & 1];
    f32x4* orow = (f32x4*)(out + (row0 + r) * OUT);
#pragma unroll
    for (int i = 0; i < 4; ++i) {
      const int q = tid + i * 1024;
      const float4 K0 = ((const float4*)k0v)[q];
      const float4 K1 = ((const float4*)k1v)[q];
      const float4 K2 = ((const float4*)k2v)[q];
      const float4 K3 = ((const float4*)k3v)[q];
      const int4 A = Am[i];
      const int4 B = Bm[i];
      float a0 = rb[A.x], b0 = rb[B.x];
      float a1 = rb[A.y], b1 = rb[B.y];
      float a2 = rb[A.z], b2 = rb[B.z];
      float a3 = rb[A.w], b3 = rb[B.w];
      f32x4 rr;
      rr.x = fmaf(K3.x, a0 * b0, fmaf(K2.x, b0, fmaf(K1.x, a0, K0.x)));
      rr.y = fmaf(K3.y, a1 * b1, fmaf(K2.y, b1, fmaf(K1.y, a1, K0.y)));
      rr.z = fmaf(K3.z, a2 * b2, fmaf(K2.z, b2, fmaf(K1.z, a2, K0.z)));
      rr.w = fmaf(K3.w, a3 * b3, fmaf(K2.w, b3, fmaf(K1.w, a3, K0.w)));
      // out is write-once/never-read: NT store keeps it from evicting x
      // from L3 (x is 256 MiB vs 256 MiB L3).
      __builtin_nontemporal_store(rr, &orow[q]);
    }
    __syncthreads();  // gather of buf[r&1] done by all; row r+1 landed
  }
}

// ---- previous proven path (generic dims): meta AoS + one row per block ----
__global__ void meta_kernel(const float* __restrict__ weights,
                            const int* __restrict__ a_idx,
                            const int* __restrict__ b_idx,
                            float4* __restrict__ k_out,
                            int2* __restrict__ idx_out, int out_dim) {
  int c = blockIdx.x * blockDim.x + threadIdx.x;
  if (c >= out_dim) return;
  float a, b, d, e;
  softmax_k(weights + (size_t)c * 16, a, b, d, e);
  k_out[c] = make_float4(a, b, d, e);
  idx_out[c] = make_int2(a_idx[c], b_idx[c]);
}

__global__ __launch_bounds__(512) void logic_main_kernel(
    const float* __restrict__ x, const float4* __restrict__ k_meta,
    const int2* __restrict__ idx_meta, float* __restrict__ out,
    int in_dim, int out_dim) {
  __shared__ float rowbuf[16384];
  const int row = blockIdx.x;
  const float4* src = (const float4*)(x + (size_t)row * in_dim);
  float4* dst = (float4*)rowbuf;
  const int n4in = in_dim >> 2;
  for (int i = threadIdx.x; i < n4in; i += 512) dst[i] = src[i];
  __syncthreads();

  float4* orow = (float4*)(out + (size_t)row * out_dim);
  const int n4out = out_dim >> 2;
  for (int q = threadIdx.x; q < n4out; q += 512) {
    const int c = q << 2;
    int2 ab0 = idx_meta[c + 0];
    int2 ab1 = idx_meta[c + 1];
    int2 ab2 = idx_meta[c + 2];
    int2 ab3 = idx_meta[c + 3];
    float4 k0 = k_meta[c + 0];
    float4 k1 = k_meta[c + 1];
    float4 k2 = k_meta[c + 2];
    float4 k3 = k_meta[c + 3];
    float a0 = rowbuf[ab0.x], b0 = rowbuf[ab0.y];
    float a1 = rowbuf[ab1.x], b1 = rowbuf[ab1.y];
    float a2 = rowbuf[ab2.x], b2 = rowbuf[ab2.y];
    float a3 = rowbuf[ab3.x], b3 = rowbuf[ab3.y];
    float4 r;
    r.x = fmaf(k0.w, a0 * b0, fmaf(k0.z, b0, fmaf(k0.y, a0, k0.x)));
    r.y = fmaf(k1.w, a1 * b1, fmaf(k1.z, b1, fmaf(k1.y, a1, k1.x)));
    r.z = fmaf(k2.w, a2 * b2, fmaf(k2.z, b2, fmaf(k2.y, a2, k2.x)));
    r.w = fmaf(k3.w, a3 * b3, fmaf(k3.z, b3, fmaf(k3.y, a3, k3.x)));
    orow[q] = r;
  }
}

// ---- fallback: fused, slow but correct ----
__global__ void fallback_kernel(const float* __restrict__ x,
                                const float* __restrict__ weights,
                                const int* __restrict__ a_idx,
                                const int* __restrict__ b_idx,
                                float* __restrict__ out, long long total,
                                int in_dim, int out_dim) {
  long long stride = (long long)gridDim.x * blockDim.x;
  for (long long t = (long long)blockIdx.x * blockDim.x + threadIdx.x;
       t < total; t += stride) {
    int c = (int)(t % out_dim);
    long long row = t / out_dim;
    float k0, k1, k2, k3;
    softmax_k(weights + (size_t)c * 16, k0, k1, k2, k3);
    float a = x[row * (size_t)in_dim + a_idx[c]];
    float b = x[row * (size_t)in_dim + b_idx[c]];
    out[t] = fmaf(k3, a * b, fmaf(k2, b, fmaf(k1, a, k0)));
  }
}

extern "C" void kernel_launch(void* const* d_in, const int* in_sizes, int n_in,
                              void* d_out, int out_size, void* d_ws,
                              size_t ws_size, hipStream_t stream) {
  const float* x = (const float*)d_in[0];
  const float* weights = (const float*)d_in[1];
  const int* a_idx = (const int*)d_in[2];
  const int* b_idx = (const int*)d_in[3];
  float* out = (float*)d_out;

  const int out_dim = in_sizes[2];         // 16384
  const int batch = out_size / out_dim;    // 4096
  const int in_dim = in_sizes[0] / batch;  // 16384

  const size_t soa_bytes = (size_t)out_dim * 24;  // 4 float + 2 int arrays
  const bool fast = (in_dim == 16384) && (out_dim == 16384) &&
                    (batch % 8 == 0) && ws_size >= soa_bytes;

  if (fast) {
    float* k0 = (float*)d_ws;
    float* k1 = k0 + out_dim;
    float* k2 = k1 + out_dim;
    float* k3 = k2 + out_dim;
    int* ai = (int*)(k3 + out_dim);
    int* bi = ai + out_dim;
    meta_soa_kernel<<<(out_dim + 255) / 256, 256, 0, stream>>>(
        weights, a_idx, b_idx, k0, k1, k2, k3, ai, bi, out_dim);
    logic_fast_kernel<<<batch / 8, 1024, 0, stream>>>(x, k0, k1, k2, k3, ai,
                                                      bi, out);
    return;
  }

  const size_t k_bytes = (size_t)out_dim * sizeof(float4);
  const size_t idx_bytes = (size_t)out_dim * sizeof(int2);
  const bool ok = ws_size >= k_bytes + idx_bytes && in_dim <= 16384 &&
                  (in_dim % 4) == 0 && (out_dim % 4) == 0;
  if (ok) {
    float4* k_meta = (float4*)d_ws;
    int2* idx_meta = (int2*)((char*)d_ws + k_bytes);
    meta_kernel<<<(out_dim + 255) / 256, 256, 0, stream>>>(
        weights, a_idx, b_idx, k_meta, idx_meta, out_dim);
    logic_main_kernel<<<batch, 512, 0, stream>>>(x, k_meta, idx_meta, out,
                                                 in_dim, out_dim);
  } else {
    long long total = (long long)batch * out_dim;
    fallback_kernel<<<4096, 256, 0, stream>>>(x, weights, a_idx, b_idx, out,
                                              total, in_dim, out_dim);
  }
}